// Round 9
// baseline (170.498 us; speedup 1.0000x reference)
//
#include <hip/hip_runtime.h>
#include <hip/hip_bf16.h>

#define N_NODES 20000
#define N_EDGES 320000
#define F_IN    128
#define F_HID   32
#define NHEAD   8
#define FDIM    256   // NHEAD * D (layer-1 feat width)
#define CAP     96    // max in-degree capacity; P(Poisson(16) > 96) ~ 1e-44

// two-level partition params
#define GROUPS  313   // ceil(N_NODES/64): coarse bin = dst>>6 (64 nodes per group)
#define GPAD    16    // gcnt padded to 1 counter per 64B line
#define GCAP    2048  // per-group record capacity
#define EPB     2048  // edges per P1 block (8 per thread)
#define P1B     ((N_EDGES + EPB - 1) / EPB)   // 157

#define TW1     12    // l1 t_w stride (floats): 48B rows, 16B-aligned for b128
#define TW2     12    // l2 t_w stride
#define L2W     8     // l2: nodes (waves) per block (round-9: was 4)

typedef __hip_bfloat16 bf16;
typedef __attribute__((ext_vector_type(8))) short short8;
typedef __attribute__((ext_vector_type(4))) float f32x4;

// bf16 round-to-nearest-even on raw bits
__device__ __forceinline__ unsigned short f2bf_rne(float f){
  unsigned u = __float_as_uint(f);
  unsigned r = u + 0x7FFFu + ((u >> 16) & 1u);
  return (unsigned short)(r >> 16);
}
__device__ __forceinline__ float bf2f(unsigned short s){
  return __uint_as_float((unsigned)s << 16);
}

// ---------------- stage 0: init ----------------
__global__ void init_kernel(const float* __restrict__ W1, const float* __restrict__ W2,
                            const float* __restrict__ al2, const float* __restrict__ ar2,
                            int* __restrict__ gcnt,
                            unsigned short* __restrict__ h1, unsigned short* __restrict__ l1,
                            float* __restrict__ q_lt, float* __restrict__ q_rt){
  const int b = blockIdx.x;
  if (b == 0){
    for (int i = threadIdx.x; i < GROUPS*GPAD; i += 256) gcnt[i] = 0;
  } else if (b < 129){
    int i = (b - 1)*256 + threadIdx.x;   // over FDIM*F_IN
    int n = i >> 7, k = i & 127;
    float v = W1[(size_t)k*FDIM + n];
    unsigned short hs = f2bf_rne(v);
    h1[i] = hs;
    l1[i] = f2bf_rne(v - bf2f(hs));
  } else {
    int t = threadIdx.x;            // t = k*8 + hh
    int k = t >> 3, hh = t & 7;
    float sl = 0.f, sr = 0.f;
    #pragma unroll
    for (int d = 0; d < 32; d++){
      float w = W2[(size_t)k*FDIM + hh*32 + d];
      sl = fmaf(w, al2[hh*32 + d], sl);
      sr = fmaf(w, ar2[hh*32 + d], sr);
    }
    q_lt[t] = sl;   // layout [k][hh]
    q_rt[t] = sr;
  }
}

// ---------------- stage 1: P1 edge-partition ∥ MFMA GEMM (fused dispatch) ----------------
#define GEMMB  (N_NODES / 16)
__global__ __launch_bounds__(256) void gemm_p1_kernel(
    const int* __restrict__ src, const int* __restrict__ dst,
    int* __restrict__ gcnt, unsigned* __restrict__ recs,
    const float* __restrict__ X,
    const unsigned short* __restrict__ Wthi, const unsigned short* __restrict__ Wtlo,
    const float* __restrict__ al, const float* __restrict__ ar,
    unsigned short* __restrict__ feat, float* __restrict__ el, float* __restrict__ er)
{
  const int b = blockIdx.x;
  const int tid = threadIdx.x;

  if (b < P1B){
    // ---- P1: coarse partition ----
    __shared__ int hist[GROUPS];   // pass 1: counts; pass 2: global cursors
    for (int t = tid; t < GROUPS; t += 256) hist[t] = 0;
    __syncthreads();

    unsigned rec[8]; int bin[8]; bool val[8];
    const int e0 = b * EPB;
    #pragma unroll
    for (int k = 0; k < 8; k++){
      int i = e0 + k*256 + tid;            // coalesced per k
      val[k] = (i < N_EDGES);
      if (val[k]){
        int s = src[i];
        int d = dst[i];
        bin[k] = d >> 6;
        rec[k] = (unsigned)(((d & 63) << 16) | s);   // src < 2^16, d_local 6b
        atomicAdd(&hist[bin[k]], 1);       // LDS atomic
      }
    }
    __syncthreads();
    {
      const int rot = (b * 97) % GROUPS;   // de-convoy: each block starts elsewhere
      for (int tt = tid; tt < GROUPS; tt += 256){
        int t = tt + rot; if (t >= GROUPS) t -= GROUPS;
        int h = hist[t];
        hist[t] = (h > 0) ? atomicAdd(&gcnt[t*GPAD], h) : 0;   // 1 line per counter
      }
    }
    __syncthreads();
    #pragma unroll
    for (int k = 0; k < 8; k++){
      if (val[k]){
        int pos = atomicAdd(&hist[bin[k]], 1);          // LDS atomic: unique slot
        if (pos < GCAP) recs[(size_t)bin[k]*GCAP + pos] = rec[k];
      }
    }
    return;
  }

  // ---- GEMM path ----
  constexpr int K = F_IN;
  const int wv   = tid >> 6;
  const int lane = tid & 63;
  const int quad = lane >> 4;
  const int l16  = lane & 15;
  const int m0   = (b - P1B) * 16;
  constexpr int NC = K / 32;

  short8 Ah[NC], Al_[NC];
  {
    const float* xrow = X + (size_t)(m0 + l16)*K;
    #pragma unroll
    for (int c = 0; c < NC; c++){
      float4 a0 = *(const float4*)(xrow + c*32 + quad*8);
      float4 a1 = *(const float4*)(xrow + c*32 + quad*8 + 4);
      const float vs[8] = {a0.x,a0.y,a0.z,a0.w,a1.x,a1.y,a1.z,a1.w};
      #pragma unroll
      for (int j = 0; j < 8; j++){
        unsigned short hs = f2bf_rne(vs[j]);
        Ah[c][j]  = (short)hs;
        Al_[c][j] = (short)f2bf_rne(vs[j] - bf2f(hs));
      }
    }
  }

  float elp[8], erp[8];   // [r*2 + hloc], hloc = tile>>1
  #pragma unroll
  for (int j = 0; j < 8; j++){ elp[j] = 0.f; erp[j] = 0.f; }

  #pragma unroll
  for (int t = 0; t < 4; t++){
    const int nc = wv*64 + t*16;
    const size_t brow = (size_t)(nc + l16) * K;
    f32x4 acc = {0.f, 0.f, 0.f, 0.f};
    #pragma unroll
    for (int c = 0; c < NC; c++){
      short8 Bh = *(const short8*)(Wthi + brow + c*32 + quad*8);
      short8 Bl = *(const short8*)(Wtlo + brow + c*32 + quad*8);
      acc = __builtin_amdgcn_mfma_f32_16x16x32_bf16(Ah[c],  Bh, acc, 0, 0, 0);
      acc = __builtin_amdgcn_mfma_f32_16x16x32_bf16(Ah[c],  Bl, acc, 0, 0, 0);
      acc = __builtin_amdgcn_mfma_f32_16x16x32_bf16(Al_[c], Bh, acc, 0, 0, 0);
    }
    const float alv = al[nc + l16];
    const float arv = ar[nc + l16];
    const int hl = t >> 1;
    #pragma unroll
    for (int r = 0; r < 4; r++){
      float v = acc[r];
      feat[(size_t)(m0 + quad*4 + r)*FDIM + nc + l16] = f2bf_rne(v);
      elp[r*2 + hl] = fmaf(v, alv, elp[r*2 + hl]);
      erp[r*2 + hl] = fmaf(v, arv, erp[r*2 + hl]);
    }
  }

  #pragma unroll
  for (int off = 1; off <= 8; off <<= 1){
    #pragma unroll
    for (int j = 0; j < 8; j++){
      elp[j] += __shfl_xor(elp[j], off);
      erp[j] += __shfl_xor(erp[j], off);
    }
  }
  __shared__ float el_lds[16][8], er_lds[16][8];
  if (l16 == 0){
    #pragma unroll
    for (int r = 0; r < 4; r++){
      #pragma unroll
      for (int hl = 0; hl < 2; hl++){
        el_lds[quad*4 + r][wv*2 + hl] = elp[r*2 + hl];
        er_lds[quad*4 + r][wv*2 + hl] = erp[r*2 + hl];
      }
    }
  }
  __syncthreads();
  if (tid < 128){
    int row = tid >> 3, h = tid & 7;
    el[(size_t)(m0 + row)*NHEAD + h] = el_lds[row][h];
    er[(size_t)(m0 + row)*NHEAD + h] = er_lds[row][h];
  }
}

// ---------------- stage 2: P2 — per-group bucket build, all-LDS ----------------
__global__ __launch_bounds__(256) void bucket_build_kernel(
    const unsigned* __restrict__ recs, const int* __restrict__ gcnt,
    int* __restrict__ cnt, int* __restrict__ bucket)
{
  const int g  = blockIdx.x;
  const int n0 = g << 6;
  __shared__ int lcnt[64];
  __shared__ int lbuck[64*CAP];      // 24 KB
  if (threadIdx.x < 64) lcnt[threadIdx.x] = 0;
  __syncthreads();

  int m = gcnt[g*GPAD]; if (m > GCAP) m = GCAP;
  for (int r = threadIdx.x; r < m; r += 256){
    unsigned w = recs[(size_t)g*GCAP + r];
    int d = (int)((w >> 16) & 63);
    int p = atomicAdd(&lcnt[d], 1);  // LDS atomic
    if (p < CAP) lbuck[d*CAP + p] = (int)(w & 0xFFFFu);
  }
  __syncthreads();

  const int nn = min(64, N_NODES - n0);
  const int d = threadIdx.x >> 2, j = threadIdx.x & 3;
  if (d < nn){
    int c = lcnt[d];
    if (j == 0) cnt[n0 + d] = c;
    if (c > CAP) c = CAP;
    const int n4 = (c + 3) >> 2;
    int4* gb = (int4*)(bucket + (size_t)(n0 + d)*CAP);
    const int4* lb = (const int4*)(lbuck + d*CAP);
    for (int i = j; i < n4; i += 4) gb[i] = lb[i];
  }
}

// ---------------- layer-1 edge softmax + aggregate ----------------
// 1-wave blocks; Phase A 1-lane/edge b128 writes; Phase B quarter-wave/edge,
// 2-deep prefetch (round-7 verified, 168.8us best).
__global__ __launch_bounds__(64, 6) void edge_agg_l1(
    const bf16* __restrict__ feat, const float* __restrict__ el,
    const float* __restrict__ er, const int* __restrict__ cnt,
    const int* __restrict__ bucket, const float* __restrict__ bias,
    const float* __restrict__ q_lt, const float* __restrict__ q_rt,
    unsigned short* __restrict__ h_out, float* __restrict__ el2,
    float* __restrict__ er2)
{
  const int lane = threadIdx.x;
  const int n    = blockIdx.x;

  __shared__ __align__(16) float t_w[CAP*TW1];   // 4608 B
  __shared__ int   s_w[CAP];
  __shared__ float sum_h[NHEAD];
  __shared__ float v_sh[256];
  __shared__ float h_sh[32];

  int C = cnt[n];
  if (C > CAP) C = CAP;

  const float4* er4 = (const float4*)(er + (size_t)n*NHEAD);
  float4 era = er4[0], erb = er4[1];
  const float erv[8] = {era.x, era.y, era.z, era.w, erb.x, erb.y, erb.z, erb.w};

  // ---- Phase A: logits, 1 lane per edge, b128 LDS writes ----
  for (int e = lane; e < C; e += 64){
    const int sidx = bucket[(size_t)n*CAP + e];
    s_w[e] = sidx;
    const float4* e4 = (const float4*)(el + (size_t)sidx*NHEAD);
    float4 a = e4[0], bq = e4[1];
    float v[8] = {a.x + erv[0], a.y + erv[1], a.z + erv[2], a.w + erv[3],
                  bq.x + erv[4], bq.y + erv[5], bq.z + erv[6], bq.w + erv[7]};
    #pragma unroll
    for (int hh = 0; hh < 8; hh++) v[hh] = (v[hh] > 0.f) ? v[hh] : 0.2f*v[hh];
    float4* tw4 = (float4*)&t_w[e*TW1];
    tw4[0] = make_float4(v[0], v[1], v[2], v[3]);
    tw4[1] = make_float4(v[4], v[5], v[6], v[7]);
  }
  // per-head max + exp + denominator: 8 lanes per head (wave-synchronous)
  {
    const int h = lane >> 3, d = lane & 7;
    float lm = -INFINITY;
    for (int e = d; e < C; e += 8) lm = fmaxf(lm, t_w[e*TW1 + h]);
    #pragma unroll
    for (int off = 4; off >= 1; off >>= 1) lm = fmaxf(lm, __shfl_xor(lm, off));
    float ls = 0.f;
    for (int e = d; e < C; e += 8){
      float ex = __expf(t_w[e*TW1 + h] - lm);
      t_w[e*TW1 + h] = ex;
      ls += ex;
    }
    #pragma unroll
    for (int off = 4; off >= 1; off >>= 1) ls += __shfl_xor(ls, off);
    if (d == 0) sum_h[h] = ls;
  }

  // ---- Phase B: quarter-wave per edge, 2-deep prefetch (8 loads in flight) ----
  const int sub  = lane >> 4;       // edge slot 0..3
  const int q    = lane & 15;       // cols [16q, 16q+16)
  const int hB   = q >> 1;          // head of this col range
  const int coff = q << 4;          // bf16 col offset
  float acc[16];
  #pragma unroll
  for (int i = 0; i < 16; i++) acc[i] = 0.f;
  int e = sub;
  float4 fa0, fb0, fa1, fb1;
  if (e < C){
    const float4* r = (const float4*)(feat + (size_t)s_w[e]*FDIM + coff);
    fa0 = r[0]; fb0 = r[1];
  }
  if (e + 4 < C){
    const float4* r = (const float4*)(feat + (size_t)s_w[e+4]*FDIM + coff);
    fa1 = r[0]; fb1 = r[1];
  }
  while (e < C){
    float4 na, nb;
    if (e + 8 < C){
      const float4* r = (const float4*)(feat + (size_t)s_w[e+8]*FDIM + coff);
      na = r[0]; nb = r[1];
    }
    const float w = t_w[e*TW1 + hB];
    const unsigned* ua = (const unsigned*)&fa0;
    const unsigned* ub = (const unsigned*)&fb0;
    #pragma unroll
    for (int j = 0; j < 4; j++){
      acc[2*j]      = fmaf(w, __uint_as_float(ua[j] << 16),        acc[2*j]);
      acc[2*j+1]    = fmaf(w, __uint_as_float(ua[j] & 0xFFFF0000u), acc[2*j+1]);
      acc[8+2*j]    = fmaf(w, __uint_as_float(ub[j] << 16),        acc[8+2*j]);
      acc[8+2*j+1]  = fmaf(w, __uint_as_float(ub[j] & 0xFFFF0000u), acc[8+2*j+1]);
    }
    fa0 = fa1; fb0 = fb1; fa1 = na; fb1 = nb;
    e += 4;
  }
  #pragma unroll
  for (int i = 0; i < 16; i++){
    acc[i] += __shfl_xor(acc[i], 16);
    acc[i] += __shfl_xor(acc[i], 32);
  }

  // ---- epilogue: divide, bias, relu -> v_sh (lanes<16, 16 cols each) ----
  if (lane < 16){
    const float s = sum_h[hB];
    const float inv = (C > 0) ? (1.f / s) : 0.f;
    const float4* b4 = (const float4*)(bias + coff);
    float4* v4 = (float4*)&v_sh[coff];
    #pragma unroll
    for (int g = 0; g < 4; g++){
      float4 bv = b4[g];
      float4 ov;
      ov.x = fmaxf(acc[4*g+0]*inv + bv.x, 0.f);
      ov.y = fmaxf(acc[4*g+1]*inv + bv.y, 0.f);
      ov.z = fmaxf(acc[4*g+2]*inv + bv.z, 0.f);
      ov.w = fmaxf(acc[4*g+3]*inv + bv.w, 0.f);
      v4[g] = ov;
    }
  }
  if (lane < 32){
    float hsum = 0.f;
    #pragma unroll
    for (int hh = 0; hh < 8; hh++) hsum += v_sh[hh*32 + lane];
    hsum *= 0.125f;                   // h[n][lane], fp32
    h_out[(size_t)n*32 + lane] = f2bf_rne(hsum);
    h_sh[lane] = hsum;
  }
  // el2/er2 = h . q columns — transposed dot: 32 lanes, one output each
  if (lane < 32){
    const int j    = lane & 7;
    const int sel  = (lane >> 3) & 1;
    const int half = lane >> 4;
    const float* qt = sel ? q_rt : q_lt;
    float p = 0.f;
    #pragma unroll
    for (int k = 0; k < 16; k++){
      const int kk = half*16 + k;
      p = fmaf(h_sh[kk], qt[kk*8 + j], p);
    }
    p += __shfl_xor(p, 16);          // combine k-halves
    if (lane < 8)       el2[(size_t)n*NHEAD + j] = p;
    else if (lane < 16) er2[(size_t)n*NHEAD + j] = p;
  }
}

// ---------------- layer-2 edge softmax + aggregate (feat2 never built) ----------------
// ROUND-9: 8 NODES (8 waves, 512 thr) PER BLOCK. The W2 epilogue is per-block
// cost (32 KB L2 reads + 2 barriers); at 4 nodes/block that was 160 MB of L2
// traffic over 5000 blocks. Now streamed once per 8 nodes (80 MB, 2500 blocks).
// Epilogue thread (half,c) covers 4 of the 8 nodes — same per-thread work as
// before. LDS 40.2KB -> 4 blocks/CU = 32 waves/CU; launch_bounds(512,8) pins
// VGPR<=64 (round-8 build used ~48). Per-wave phases unchanged.
__global__ __launch_bounds__(512, 8) void edge_agg_l2(
    const unsigned short* __restrict__ h_bf, const float* __restrict__ el2,
    const float* __restrict__ er2, const int* __restrict__ cnt,
    const int* __restrict__ bucket, const float* __restrict__ W2,
    const float* __restrict__ b2, float* __restrict__ outp)
{
  const int tid  = threadIdx.x;
  const int wv   = tid >> 6;
  const int lane = tid & 63;
  const int n    = blockIdx.x*L2W + wv;

  __shared__ __align__(16) float t_all[L2W][CAP*TW2];   // 8 slabs x 1152 floats
  __shared__ int   s_all[L2W][CAP];
  __shared__ float sum_all[L2W][NHEAD];
  float* t_w = t_all[wv];
  int*   s_w = s_all[wv];

  int C = cnt[n];
  if (C > CAP) C = CAP;

  const float4* er4 = (const float4*)(er2 + (size_t)n*NHEAD);
  float4 era = er4[0], erb = er4[1];
  const float erv[8] = {era.x, era.y, era.z, era.w, erb.x, erb.y, erb.z, erb.w};

  // ---- Phase A: logits, 1 lane per edge, b128 LDS writes ----
  for (int e = lane; e < C; e += 64){
    const int sidx = bucket[(size_t)n*CAP + e];
    s_w[e] = sidx;
    const float4* e4 = (const float4*)(el2 + (size_t)sidx*NHEAD);
    float4 a = e4[0], bq = e4[1];
    float v[8] = {a.x + erv[0], a.y + erv[1], a.z + erv[2], a.w + erv[3],
                  bq.x + erv[4], bq.y + erv[5], bq.z + erv[6], bq.w + erv[7]};
    #pragma unroll
    for (int hh = 0; hh < 8; hh++) v[hh] = (v[hh] > 0.f) ? v[hh] : 0.2f*v[hh];
    float4* tw4 = (float4*)&t_w[e*TW2];
    tw4[0] = make_float4(v[0], v[1], v[2], v[3]);
    tw4[1] = make_float4(v[4], v[5], v[6], v[7]);
  }
  // per-head max + exp + denominator
  {
    const int h = lane >> 3, d = lane & 7;
    float lm = -INFINITY;
    for (int e = d; e < C; e += 8) lm = fmaxf(lm, t_w[e*TW2 + h]);
    #pragma unroll
    for (int off = 4; off >= 1; off >>= 1) lm = fmaxf(lm, __shfl_xor(lm, off));
    float ls = 0.f;
    for (int e = d; e < C; e += 8){
      float ex = __expf(t_w[e*TW2 + h] - lm);
      t_w[e*TW2 + h] = ex;
      ls += ex;
    }
    #pragma unroll
    for (int off = 4; off >= 1; off >>= 1) ls += __shfl_xor(ls, off);
    if (d == 0) sum_all[wv][h] = ls;
  }

  // ---- Phase B: quarter-wave per edge, 2-deep prefetch ----
  const int sub = lane >> 4;        // 4 edge slots
  const int q   = lane & 15;        // dims 2q, 2q+1
  float acc[16];
  #pragma unroll
  for (int i = 0; i < 16; i++) acc[i] = 0.f;
  int e = sub;
  unsigned hv0, hv1;
  if (e < C)     hv0 = *(const unsigned*)(h_bf + (size_t)s_w[e]*32 + q*2);
  if (e + 4 < C) hv1 = *(const unsigned*)(h_bf + (size_t)s_w[e+4]*32 + q*2);
  while (e < C){
    unsigned hn;
    if (e + 8 < C) hn = *(const unsigned*)(h_bf + (size_t)s_w[e+8]*32 + q*2);
    f32x4 w0 = *(const f32x4*)&t_w[e*TW2];      // heads 0..3 (ds_read_b128)
    f32x4 w1 = *(const f32x4*)&t_w[e*TW2 + 4];  // heads 4..7
    const float x0 = __uint_as_float(hv0 << 16);
    const float x1 = __uint_as_float(hv0 & 0xFFFF0000u);
    #pragma unroll
    for (int h = 0; h < 4; h++){
      acc[2*h]     = fmaf(w0[h], x0, acc[2*h]);
      acc[2*h+1]   = fmaf(w0[h], x1, acc[2*h+1]);
      acc[8+2*h]   = fmaf(w1[h], x0, acc[8+2*h]);
      acc[8+2*h+1] = fmaf(w1[h], x1, acc[8+2*h+1]);
    }
    hv0 = hv1; hv1 = hn;
    e += 4;
  }
  #pragma unroll
  for (int i = 0; i < 16; i++){
    acc[i] += __shfl_xor(acc[i], 16);
    acc[i] += __shfl_xor(acc[i], 32);
  }
  // write A into own (now dead) t_w slab
  if (lane < 16){
    #pragma unroll
    for (int h = 0; h < 8; h++){
      const float s = sum_all[wv][h];
      const float inv = (C > 0) ? (1.f / s) : 0.f;
      t_w[h*33 + 2*lane]     = acc[2*h]   * inv;
      t_w[h*33 + 2*lane + 1] = acc[2*h+1] * inv;
    }
  }
  __syncthreads();   // all 8 waves' A ready

  // ---- block-cooperative epilogue: (half, c) covers nodes half*4..+3 ----
  {
    const int c    = tid & 255;     // column = h*32 + d
    const int half = tid >> 8;      // 0 or 1
    const int hc   = c >> 5;
    const int base = half*4;
    float p0=0.f, p1=0.f, p2=0.f, p3=0.f;
    for (int k = 0; k < F_HID; k++){
      float w = W2[(size_t)k*FDIM + c];     // 1 KB/k per block, broadcast to both halves
      p0 = fmaf(t_all[base+0][hc*33 + k], w, p0);
      p1 = fmaf(t_all[base+1][hc*33 + k], w, p1);
      p2 = fmaf(t_all[base+2][hc*33 + k], w, p2);
      p3 = fmaf(t_all[base+3][hc*33 + k], w, p3);
    }
    t_all[base+0][512 + c] = p0;   // red regions (disjoint from A regions)
    t_all[base+1][512 + c] = p1;
    t_all[base+2][512 + c] = p2;
    t_all[base+3][512 + c] = p3;
  }
  __syncthreads();
  if (tid < 256){
    const int nn = tid >> 5, d = tid & 31;
    float s = 0.f, bm = 0.f;
    #pragma unroll
    for (int hh = 0; hh < 8; hh++){
      s  += t_all[nn][512 + hh*32 + d];
      bm += b2[hh*32 + d];
    }
    outp[(size_t)(blockIdx.x*L2W + nn)*32 + d] = (s + bm) * 0.125f;
  }
}

extern "C" void kernel_launch(void* const* d_in, const int* in_sizes, int n_in,
                              void* d_out, int out_size, void* d_ws, size_t ws_size,
                              hipStream_t stream)
{
  const float* x   = (const float*)d_in[0];
  const int*   src = (const int*)  d_in[1];
  const int*   dst = (const int*)  d_in[2];
  const float* W1  = (const float*)d_in[3];
  const float* al1 = (const float*)d_in[4];
  const float* ar1 = (const float*)d_in[5];
  const float* b1  = (const float*)d_in[6];
  const float* W2  = (const float*)d_in[7];
  const float* al2 = (const float*)d_in[8];
  const float* ar2 = (const float*)d_in[9];
  const float* b2  = (const float*)d_in[10];
  (void)in_sizes; (void)n_in; (void)out_size; (void)ws_size;

  size_t o = 0;
  char* base = (char*)d_ws;
  auto take = [&](size_t bytes) -> char* {
    char* p = base + o;
    o += (bytes + 255) & ~(size_t)255;
    return p;
  };
  unsigned short* feat  = (unsigned short*)take((size_t)N_NODES*FDIM*2);
  float* el1    = (float*)take((size_t)N_NODES*NHEAD*4);
  float* er1    = (float*)take((size_t)N_NODES*NHEAD*4);
  float* el2    = (float*)take((size_t)N_NODES*NHEAD*4);
  float* er2    = (float*)take((size_t)N_NODES*NHEAD*4);
  int*   cnt    = (int*)  take((size_t)N_NODES*4);
  int*   bucket = (int*)  take((size_t)N_NODES*CAP*4);
  unsigned short* hbf  = (unsigned short*)take((size_t)N_NODES*F_HID*2);
  unsigned short* W1th = (unsigned short*)take((size_t)FDIM*F_IN*2);
  unsigned short* W1tl = (unsigned short*)take((size_t)FDIM*F_IN*2);
  float* q_lt   = (float*)take((size_t)F_HID*NHEAD*4);
  float* q_rt   = (float*)take((size_t)F_HID*NHEAD*4);
  int*   gcnt   = (int*)  take((size_t)GROUPS*GPAD*4);
  unsigned* recs = (unsigned*)take((size_t)GROUPS*GCAP*4);

  // stage 0: gcnt=0 + W1 transpose + q projections
  init_kernel<<<130, 256, 0, stream>>>(
      W1, W2, al2, ar2, gcnt, W1th, W1tl, q_lt, q_rt);

  // stage 1: coarse edge partition ∥ layer-1 GEMM (independent, fused dispatch)
  gemm_p1_kernel<<<P1B + GEMMB, 256, 0, stream>>>(
      src, dst, gcnt, recs, x, W1th, W1tl, al1, ar1, feat, el1, er1);

  // stage 2: per-group LDS bucket build (no global atomics, sparse flush)
  bucket_build_kernel<<<GROUPS, 256, 0, stream>>>(recs, gcnt, cnt, bucket);

  // stage 3: layer-1 softmax + aggregate (1-wave blocks, no barriers)
  edge_agg_l1<<<N_NODES, 64, 0, stream>>>(
      (const bf16*)feat, el1, er1, cnt, bucket, b1, q_lt, q_rt, hbf, el2, er2);

  // stage 4: layer-2 softmax + aggregate (8 nodes/block, amortized W2 epilogue)
  edge_agg_l2<<<N_NODES/L2W, 512, 0, stream>>>(
      hbf, el2, er2, cnt, bucket, W2, b2, (float*)d_out);
}

// Round 10
// 169.306 us; speedup vs baseline: 1.0070x; 1.0070x over previous
//
#include <hip/hip_runtime.h>
#include <hip/hip_bf16.h>

#define N_NODES 20000
#define N_EDGES 320000
#define F_IN    128
#define F_HID   32
#define NHEAD   8
#define FDIM    256   // NHEAD * D (layer-1 feat width)
#define CAP     96    // max in-degree capacity; P(Poisson(16) > 96) ~ 1e-44

// two-level partition params
#define GROUPS  313   // ceil(N_NODES/64): coarse bin = dst>>6 (64 nodes per group)
#define GPAD    16    // gcnt padded to 1 counter per 64B line
#define GCAP    2048  // per-group record capacity
#define EPB     2048  // edges per P1 block (8 per thread)
#define P1B     ((N_EDGES + EPB - 1) / EPB)   // 157

#define TW1     12    // l1 t_w stride (floats): 48B rows, 16B-aligned for b128
#define TW2     12    // l2 t_w stride

typedef __hip_bfloat16 bf16;
typedef __attribute__((ext_vector_type(8))) short short8;
typedef __attribute__((ext_vector_type(4))) float f32x4;

// bf16 round-to-nearest-even on raw bits
__device__ __forceinline__ unsigned short f2bf_rne(float f){
  unsigned u = __float_as_uint(f);
  unsigned r = u + 0x7FFFu + ((u >> 16) & 1u);
  return (unsigned short)(r >> 16);
}
__device__ __forceinline__ float bf2f(unsigned short s){
  return __uint_as_float((unsigned)s << 16);
}

// ---------------- stage 0: init ----------------
__global__ void init_kernel(const float* __restrict__ W1, const float* __restrict__ W2,
                            const float* __restrict__ al2, const float* __restrict__ ar2,
                            int* __restrict__ gcnt,
                            unsigned short* __restrict__ h1, unsigned short* __restrict__ l1,
                            float* __restrict__ q_lt, float* __restrict__ q_rt){
  const int b = blockIdx.x;
  if (b == 0){
    for (int i = threadIdx.x; i < GROUPS*GPAD; i += 256) gcnt[i] = 0;
  } else if (b < 129){
    int i = (b - 1)*256 + threadIdx.x;   // over FDIM*F_IN
    int n = i >> 7, k = i & 127;
    float v = W1[(size_t)k*FDIM + n];
    unsigned short hs = f2bf_rne(v);
    h1[i] = hs;
    l1[i] = f2bf_rne(v - bf2f(hs));
  } else {
    int t = threadIdx.x;            // t = k*8 + hh
    int k = t >> 3, hh = t & 7;
    float sl = 0.f, sr = 0.f;
    #pragma unroll
    for (int d = 0; d < 32; d++){
      float w = W2[(size_t)k*FDIM + hh*32 + d];
      sl = fmaf(w, al2[hh*32 + d], sl);
      sr = fmaf(w, ar2[hh*32 + d], sr);
    }
    q_lt[t] = sl;   // layout [k][hh]
    q_rt[t] = sr;
  }
}

// ---------------- stage 1: P1 edge-partition ∥ MFMA GEMM (fused dispatch) ----------------
#define GEMMB  (N_NODES / 16)
__global__ __launch_bounds__(256) void gemm_p1_kernel(
    const int* __restrict__ src, const int* __restrict__ dst,
    int* __restrict__ gcnt, unsigned* __restrict__ recs,
    const float* __restrict__ X,
    const unsigned short* __restrict__ Wthi, const unsigned short* __restrict__ Wtlo,
    const float* __restrict__ al, const float* __restrict__ ar,
    unsigned short* __restrict__ feat, float* __restrict__ el, float* __restrict__ er)
{
  const int b = blockIdx.x;
  const int tid = threadIdx.x;

  if (b < P1B){
    // ---- P1: coarse partition ----
    __shared__ int hist[GROUPS];   // pass 1: counts; pass 2: global cursors
    for (int t = tid; t < GROUPS; t += 256) hist[t] = 0;
    __syncthreads();

    unsigned rec[8]; int bin[8]; bool val[8];
    const int e0 = b * EPB;
    #pragma unroll
    for (int k = 0; k < 8; k++){
      int i = e0 + k*256 + tid;            // coalesced per k
      val[k] = (i < N_EDGES);
      if (val[k]){
        int s = src[i];
        int d = dst[i];
        bin[k] = d >> 6;
        rec[k] = (unsigned)(((d & 63) << 16) | s);   // src < 2^16, d_local 6b
        atomicAdd(&hist[bin[k]], 1);       // LDS atomic
      }
    }
    __syncthreads();
    {
      const int rot = (b * 97) % GROUPS;   // de-convoy: each block starts elsewhere
      for (int tt = tid; tt < GROUPS; tt += 256){
        int t = tt + rot; if (t >= GROUPS) t -= GROUPS;
        int h = hist[t];
        hist[t] = (h > 0) ? atomicAdd(&gcnt[t*GPAD], h) : 0;   // 1 line per counter
      }
    }
    __syncthreads();
    #pragma unroll
    for (int k = 0; k < 8; k++){
      if (val[k]){
        int pos = atomicAdd(&hist[bin[k]], 1);          // LDS atomic: unique slot
        if (pos < GCAP) recs[(size_t)bin[k]*GCAP + pos] = rec[k];
      }
    }
    return;
  }

  // ---- GEMM path ----
  constexpr int K = F_IN;
  const int wv   = tid >> 6;
  const int lane = tid & 63;
  const int quad = lane >> 4;
  const int l16  = lane & 15;
  const int m0   = (b - P1B) * 16;
  constexpr int NC = K / 32;

  short8 Ah[NC], Al_[NC];
  {
    const float* xrow = X + (size_t)(m0 + l16)*K;
    #pragma unroll
    for (int c = 0; c < NC; c++){
      float4 a0 = *(const float4*)(xrow + c*32 + quad*8);
      float4 a1 = *(const float4*)(xrow + c*32 + quad*8 + 4);
      const float vs[8] = {a0.x,a0.y,a0.z,a0.w,a1.x,a1.y,a1.z,a1.w};
      #pragma unroll
      for (int j = 0; j < 8; j++){
        unsigned short hs = f2bf_rne(vs[j]);
        Ah[c][j]  = (short)hs;
        Al_[c][j] = (short)f2bf_rne(vs[j] - bf2f(hs));
      }
    }
  }

  float elp[8], erp[8];   // [r*2 + hloc], hloc = tile>>1
  #pragma unroll
  for (int j = 0; j < 8; j++){ elp[j] = 0.f; erp[j] = 0.f; }

  #pragma unroll
  for (int t = 0; t < 4; t++){
    const int nc = wv*64 + t*16;
    const size_t brow = (size_t)(nc + l16) * K;
    f32x4 acc = {0.f, 0.f, 0.f, 0.f};
    #pragma unroll
    for (int c = 0; c < NC; c++){
      short8 Bh = *(const short8*)(Wthi + brow + c*32 + quad*8);
      short8 Bl = *(const short8*)(Wtlo + brow + c*32 + quad*8);
      acc = __builtin_amdgcn_mfma_f32_16x16x32_bf16(Ah[c],  Bh, acc, 0, 0, 0);
      acc = __builtin_amdgcn_mfma_f32_16x16x32_bf16(Ah[c],  Bl, acc, 0, 0, 0);
      acc = __builtin_amdgcn_mfma_f32_16x16x32_bf16(Al_[c], Bh, acc, 0, 0, 0);
    }
    const float alv = al[nc + l16];
    const float arv = ar[nc + l16];
    const int hl = t >> 1;
    #pragma unroll
    for (int r = 0; r < 4; r++){
      float v = acc[r];
      feat[(size_t)(m0 + quad*4 + r)*FDIM + nc + l16] = f2bf_rne(v);
      elp[r*2 + hl] = fmaf(v, alv, elp[r*2 + hl]);
      erp[r*2 + hl] = fmaf(v, arv, erp[r*2 + hl]);
    }
  }

  #pragma unroll
  for (int off = 1; off <= 8; off <<= 1){
    #pragma unroll
    for (int j = 0; j < 8; j++){
      elp[j] += __shfl_xor(elp[j], off);
      erp[j] += __shfl_xor(erp[j], off);
    }
  }
  __shared__ float el_lds[16][8], er_lds[16][8];
  if (l16 == 0){
    #pragma unroll
    for (int r = 0; r < 4; r++){
      #pragma unroll
      for (int hl = 0; hl < 2; hl++){
        el_lds[quad*4 + r][wv*2 + hl] = elp[r*2 + hl];
        er_lds[quad*4 + r][wv*2 + hl] = erp[r*2 + hl];
      }
    }
  }
  __syncthreads();
  if (tid < 128){
    int row = tid >> 3, h = tid & 7;
    el[(size_t)(m0 + row)*NHEAD + h] = el_lds[row][h];
    er[(size_t)(m0 + row)*NHEAD + h] = er_lds[row][h];
  }
}

// ---------------- stage 2: P2 — per-group bucket build, all-LDS ----------------
__global__ __launch_bounds__(256) void bucket_build_kernel(
    const unsigned* __restrict__ recs, const int* __restrict__ gcnt,
    int* __restrict__ cnt, int* __restrict__ bucket)
{
  const int g  = blockIdx.x;
  const int n0 = g << 6;
  __shared__ int lcnt[64];
  __shared__ int lbuck[64*CAP];      // 24 KB
  if (threadIdx.x < 64) lcnt[threadIdx.x] = 0;
  __syncthreads();

  int m = gcnt[g*GPAD]; if (m > GCAP) m = GCAP;
  for (int r = threadIdx.x; r < m; r += 256){
    unsigned w = recs[(size_t)g*GCAP + r];
    int d = (int)((w >> 16) & 63);
    int p = atomicAdd(&lcnt[d], 1);  // LDS atomic
    if (p < CAP) lbuck[d*CAP + p] = (int)(w & 0xFFFFu);
  }
  __syncthreads();

  const int nn = min(64, N_NODES - n0);
  const int d = threadIdx.x >> 2, j = threadIdx.x & 3;
  if (d < nn){
    int c = lcnt[d];
    if (j == 0) cnt[n0 + d] = c;
    if (c > CAP) c = CAP;
    const int n4 = (c + 3) >> 2;
    int4* gb = (int4*)(bucket + (size_t)(n0 + d)*CAP);
    const int4* lb = (const int4*)(lbuck + d*CAP);
    for (int i = j; i < n4; i += 4) gb[i] = lb[i];
  }
}

// ---------------- layer-1 edge softmax + aggregate ----------------
// 1-wave blocks; Phase A 1-lane/edge b128 writes; Phase B quarter-wave/edge,
// 2-deep prefetch (round-7 verified, 168.8us best).
__global__ __launch_bounds__(64, 6) void edge_agg_l1(
    const bf16* __restrict__ feat, const float* __restrict__ el,
    const float* __restrict__ er, const int* __restrict__ cnt,
    const int* __restrict__ bucket, const float* __restrict__ bias,
    const float* __restrict__ q_lt, const float* __restrict__ q_rt,
    unsigned short* __restrict__ h_out, float* __restrict__ el2,
    float* __restrict__ er2)
{
  const int lane = threadIdx.x;
  const int n    = blockIdx.x;

  __shared__ __align__(16) float t_w[CAP*TW1];   // 4608 B
  __shared__ int   s_w[CAP];
  __shared__ float sum_h[NHEAD];
  __shared__ float v_sh[256];
  __shared__ float h_sh[32];

  int C = cnt[n];
  if (C > CAP) C = CAP;

  const float4* er4 = (const float4*)(er + (size_t)n*NHEAD);
  float4 era = er4[0], erb = er4[1];
  const float erv[8] = {era.x, era.y, era.z, era.w, erb.x, erb.y, erb.z, erb.w};

  // ---- Phase A: logits, 1 lane per edge, b128 LDS writes ----
  for (int e = lane; e < C; e += 64){
    const int sidx = bucket[(size_t)n*CAP + e];
    s_w[e] = sidx;
    const float4* e4 = (const float4*)(el + (size_t)sidx*NHEAD);
    float4 a = e4[0], bq = e4[1];
    float v[8] = {a.x + erv[0], a.y + erv[1], a.z + erv[2], a.w + erv[3],
                  bq.x + erv[4], bq.y + erv[5], bq.z + erv[6], bq.w + erv[7]};
    #pragma unroll
    for (int hh = 0; hh < 8; hh++) v[hh] = (v[hh] > 0.f) ? v[hh] : 0.2f*v[hh];
    float4* tw4 = (float4*)&t_w[e*TW1];
    tw4[0] = make_float4(v[0], v[1], v[2], v[3]);
    tw4[1] = make_float4(v[4], v[5], v[6], v[7]);
  }
  // per-head max + exp + denominator: 8 lanes per head (wave-synchronous)
  {
    const int h = lane >> 3, d = lane & 7;
    float lm = -INFINITY;
    for (int e = d; e < C; e += 8) lm = fmaxf(lm, t_w[e*TW1 + h]);
    #pragma unroll
    for (int off = 4; off >= 1; off >>= 1) lm = fmaxf(lm, __shfl_xor(lm, off));
    float ls = 0.f;
    for (int e = d; e < C; e += 8){
      float ex = __expf(t_w[e*TW1 + h] - lm);
      t_w[e*TW1 + h] = ex;
      ls += ex;
    }
    #pragma unroll
    for (int off = 4; off >= 1; off >>= 1) ls += __shfl_xor(ls, off);
    if (d == 0) sum_h[h] = ls;
  }

  // ---- Phase B: quarter-wave per edge, 2-deep prefetch (8 loads in flight) ----
  const int sub  = lane >> 4;       // edge slot 0..3
  const int q    = lane & 15;       // cols [16q, 16q+16)
  const int hB   = q >> 1;          // head of this col range
  const int coff = q << 4;          // bf16 col offset
  float acc[16];
  #pragma unroll
  for (int i = 0; i < 16; i++) acc[i] = 0.f;
  int e = sub;
  float4 fa0, fb0, fa1, fb1;
  if (e < C){
    const float4* r = (const float4*)(feat + (size_t)s_w[e]*FDIM + coff);
    fa0 = r[0]; fb0 = r[1];
  }
  if (e + 4 < C){
    const float4* r = (const float4*)(feat + (size_t)s_w[e+4]*FDIM + coff);
    fa1 = r[0]; fb1 = r[1];
  }
  while (e < C){
    float4 na, nb;
    if (e + 8 < C){
      const float4* r = (const float4*)(feat + (size_t)s_w[e+8]*FDIM + coff);
      na = r[0]; nb = r[1];
    }
    const float w = t_w[e*TW1 + hB];
    const unsigned* ua = (const unsigned*)&fa0;
    const unsigned* ub = (const unsigned*)&fb0;
    #pragma unroll
    for (int j = 0; j < 4; j++){
      acc[2*j]      = fmaf(w, __uint_as_float(ua[j] << 16),        acc[2*j]);
      acc[2*j+1]    = fmaf(w, __uint_as_float(ua[j] & 0xFFFF0000u), acc[2*j+1]);
      acc[8+2*j]    = fmaf(w, __uint_as_float(ub[j] << 16),        acc[8+2*j]);
      acc[8+2*j+1]  = fmaf(w, __uint_as_float(ub[j] & 0xFFFF0000u), acc[8+2*j+1]);
    }
    fa0 = fa1; fb0 = fb1; fa1 = na; fb1 = nb;
    e += 4;
  }
  #pragma unroll
  for (int i = 0; i < 16; i++){
    acc[i] += __shfl_xor(acc[i], 16);
    acc[i] += __shfl_xor(acc[i], 32);
  }

  // ---- epilogue: divide, bias, relu -> v_sh (lanes<16, 16 cols each) ----
  if (lane < 16){
    const float s = sum_h[hB];
    const float inv = (C > 0) ? (1.f / s) : 0.f;
    const float4* b4 = (const float4*)(bias + coff);
    float4* v4 = (float4*)&v_sh[coff];
    #pragma unroll
    for (int g = 0; g < 4; g++){
      float4 bv = b4[g];
      float4 ov;
      ov.x = fmaxf(acc[4*g+0]*inv + bv.x, 0.f);
      ov.y = fmaxf(acc[4*g+1]*inv + bv.y, 0.f);
      ov.z = fmaxf(acc[4*g+2]*inv + bv.z, 0.f);
      ov.w = fmaxf(acc[4*g+3]*inv + bv.w, 0.f);
      v4[g] = ov;
    }
  }
  if (lane < 32){
    float hsum = 0.f;
    #pragma unroll
    for (int hh = 0; hh < 8; hh++) hsum += v_sh[hh*32 + lane];
    hsum *= 0.125f;                   // h[n][lane], fp32
    h_out[(size_t)n*32 + lane] = f2bf_rne(hsum);
    h_sh[lane] = hsum;
  }
  // el2/er2 = h . q columns — transposed dot: 32 lanes, one output each
  if (lane < 32){
    const int j    = lane & 7;
    const int sel  = (lane >> 3) & 1;
    const int half = lane >> 4;
    const float* qt = sel ? q_rt : q_lt;
    float p = 0.f;
    #pragma unroll
    for (int k = 0; k < 16; k++){
      const int kk = half*16 + k;
      p = fmaf(h_sh[kk], qt[kk*8 + j], p);
    }
    p += __shfl_xor(p, 16);          // combine k-halves
    if (lane < 8)       el2[(size_t)n*NHEAD + j] = p;
    else if (lane < 16) er2[(size_t)n*NHEAD + j] = p;
  }
}

// ---------------- layer-2 edge softmax + aggregate (feat2 never built) ----------------
// ROUND-10: revert to round-8 config (4 nodes/256thr, measured best 167.7us).
// Round-9's 8-node block regressed +2.8us: the pre-epilogue barrier waits on
// the slowest of 8 Poisson(16) waves vs 4 — barrier slack grew faster than the
// W2 L2-stream amortization saved (~5us total at 34TB/s L2).
// Phase A: 1 lane/edge b128 writes; Phase B: 2-deep prefetch (round-8).
// A_lds/red alias the dead t_w slab (round-3): LDS 19.6 KB.
__global__ __launch_bounds__(256, 6) void edge_agg_l2(
    const unsigned short* __restrict__ h_bf, const float* __restrict__ el2,
    const float* __restrict__ er2, const int* __restrict__ cnt,
    const int* __restrict__ bucket, const float* __restrict__ W2,
    const float* __restrict__ b2, float* __restrict__ outp)
{
  const int tid  = threadIdx.x;
  const int wv   = tid >> 6;
  const int lane = tid & 63;
  const int n    = blockIdx.x*4 + wv;

  __shared__ __align__(16) float t_all[4][CAP*TW2];   // 1152 floats per slab
  __shared__ int   s_all[4][CAP];
  __shared__ float sum_all[4][NHEAD];
  float* t_w = t_all[wv];
  int*   s_w = s_all[wv];

  int C = cnt[n];
  if (C > CAP) C = CAP;

  const float4* er4 = (const float4*)(er2 + (size_t)n*NHEAD);
  float4 era = er4[0], erb = er4[1];
  const float erv[8] = {era.x, era.y, era.z, era.w, erb.x, erb.y, erb.z, erb.w};

  // ---- Phase A: logits, 1 lane per edge, b128 LDS writes ----
  for (int e = lane; e < C; e += 64){
    const int sidx = bucket[(size_t)n*CAP + e];
    s_w[e] = sidx;
    const float4* e4 = (const float4*)(el2 + (size_t)sidx*NHEAD);
    float4 a = e4[0], bq = e4[1];
    float v[8] = {a.x + erv[0], a.y + erv[1], a.z + erv[2], a.w + erv[3],
                  bq.x + erv[4], bq.y + erv[5], bq.z + erv[6], bq.w + erv[7]};
    #pragma unroll
    for (int hh = 0; hh < 8; hh++) v[hh] = (v[hh] > 0.f) ? v[hh] : 0.2f*v[hh];
    float4* tw4 = (float4*)&t_w[e*TW2];
    tw4[0] = make_float4(v[0], v[1], v[2], v[3]);
    tw4[1] = make_float4(v[4], v[5], v[6], v[7]);
  }
  // per-head max + exp + denominator
  {
    const int h = lane >> 3, d = lane & 7;
    float lm = -INFINITY;
    for (int e = d; e < C; e += 8) lm = fmaxf(lm, t_w[e*TW2 + h]);
    #pragma unroll
    for (int off = 4; off >= 1; off >>= 1) lm = fmaxf(lm, __shfl_xor(lm, off));
    float ls = 0.f;
    for (int e = d; e < C; e += 8){
      float ex = __expf(t_w[e*TW2 + h] - lm);
      t_w[e*TW2 + h] = ex;
      ls += ex;
    }
    #pragma unroll
    for (int off = 4; off >= 1; off >>= 1) ls += __shfl_xor(ls, off);
    if (d == 0) sum_all[wv][h] = ls;
  }

  // ---- Phase B: quarter-wave per edge, 2-deep prefetch ----
  const int sub = lane >> 4;        // 4 edge slots
  const int q   = lane & 15;        // dims 2q, 2q+1
  float acc[16];
  #pragma unroll
  for (int i = 0; i < 16; i++) acc[i] = 0.f;
  int e = sub;
  unsigned hv0, hv1;
  if (e < C)     hv0 = *(const unsigned*)(h_bf + (size_t)s_w[e]*32 + q*2);
  if (e + 4 < C) hv1 = *(const unsigned*)(h_bf + (size_t)s_w[e+4]*32 + q*2);
  while (e < C){
    unsigned hn;
    if (e + 8 < C) hn = *(const unsigned*)(h_bf + (size_t)s_w[e+8]*32 + q*2);
    f32x4 w0 = *(const f32x4*)&t_w[e*TW2];      // heads 0..3 (ds_read_b128)
    f32x4 w1 = *(const f32x4*)&t_w[e*TW2 + 4];  // heads 4..7
    const float x0 = __uint_as_float(hv0 << 16);
    const float x1 = __uint_as_float(hv0 & 0xFFFF0000u);
    #pragma unroll
    for (int h = 0; h < 4; h++){
      acc[2*h]     = fmaf(w0[h], x0, acc[2*h]);
      acc[2*h+1]   = fmaf(w0[h], x1, acc[2*h+1]);
      acc[8+2*h]   = fmaf(w1[h], x0, acc[8+2*h]);
      acc[8+2*h+1] = fmaf(w1[h], x1, acc[8+2*h+1]);
    }
    hv0 = hv1; hv1 = hn;
    e += 4;
  }
  #pragma unroll
  for (int i = 0; i < 16; i++){
    acc[i] += __shfl_xor(acc[i], 16);
    acc[i] += __shfl_xor(acc[i], 32);
  }
  // write A into own (now dead) t_w slab
  if (lane < 16){
    #pragma unroll
    for (int h = 0; h < 8; h++){
      const float s = sum_all[wv][h];
      const float inv = (C > 0) ? (1.f / s) : 0.f;
      t_w[h*33 + 2*lane]     = acc[2*h]   * inv;
      t_w[h*33 + 2*lane + 1] = acc[2*h+1] * inv;
    }
  }
  __syncthreads();   // all 4 waves' A ready

  // ---- block-cooperative epilogue: c = tid = h*32+d; coalesced W2[k][c] ----
  {
    const int c  = tid;
    const int hc = c >> 5;
    float p0=0.f, p1=0.f, p2=0.f, p3=0.f;
    for (int k = 0; k < F_HID; k++){
      float w = W2[(size_t)k*FDIM + c];     // 1 KB coalesced per k per block
      p0 = fmaf(t_all[0][hc*33 + k], w, p0);    // LDS broadcast reads (A regions)
      p1 = fmaf(t_all[1][hc*33 + k], w, p1);
      p2 = fmaf(t_all[2][hc*33 + k], w, p2);
      p3 = fmaf(t_all[3][hc*33 + k], w, p3);
    }
    t_all[0][512 + c] = p0;   // red regions (disjoint from A regions)
    t_all[1][512 + c] = p1;
    t_all[2][512 + c] = p2;
    t_all[3][512 + c] = p3;
  }
  __syncthreads();
  if (tid < 128){
    const int nn = tid >> 5, d = tid & 31;
    float s = 0.f, bm = 0.f;
    #pragma unroll
    for (int hh = 0; hh < 8; hh++){
      s  += t_all[nn][512 + hh*32 + d];
      bm += b2[hh*32 + d];
    }
    outp[(size_t)(blockIdx.x*4 + nn)*32 + d] = (s + bm) * 0.125f;
  }
}

extern "C" void kernel_launch(void* const* d_in, const int* in_sizes, int n_in,
                              void* d_out, int out_size, void* d_ws, size_t ws_size,
                              hipStream_t stream)
{
  const float* x   = (const float*)d_in[0];
  const int*   src = (const int*)  d_in[1];
  const int*   dst = (const int*)  d_in[2];
  const float* W1  = (const float*)d_in[3];
  const float* al1 = (const float*)d_in[4];
  const float* ar1 = (const float*)d_in[5];
  const float* b1  = (const float*)d_in[6];
  const float* W2  = (const float*)d_in[7];
  const float* al2 = (const float*)d_in[8];
  const float* ar2 = (const float*)d_in[9];
  const float* b2  = (const float*)d_in[10];
  (void)in_sizes; (void)n_in; (void)out_size; (void)ws_size;

  size_t o = 0;
  char* base = (char*)d_ws;
  auto take = [&](size_t bytes) -> char* {
    char* p = base + o;
    o += (bytes + 255) & ~(size_t)255;
    return p;
  };
  unsigned short* feat  = (unsigned short*)take((size_t)N_NODES*FDIM*2);
  float* el1    = (float*)take((size_t)N_NODES*NHEAD*4);
  float* er1    = (float*)take((size_t)N_NODES*NHEAD*4);
  float* el2    = (float*)take((size_t)N_NODES*NHEAD*4);
  float* er2    = (float*)take((size_t)N_NODES*NHEAD*4);
  int*   cnt    = (int*)  take((size_t)N_NODES*4);
  int*   bucket = (int*)  take((size_t)N_NODES*CAP*4);
  unsigned short* hbf  = (unsigned short*)take((size_t)N_NODES*F_HID*2);
  unsigned short* W1th = (unsigned short*)take((size_t)FDIM*F_IN*2);
  unsigned short* W1tl = (unsigned short*)take((size_t)FDIM*F_IN*2);
  float* q_lt   = (float*)take((size_t)F_HID*NHEAD*4);
  float* q_rt   = (float*)take((size_t)F_HID*NHEAD*4);
  int*   gcnt   = (int*)  take((size_t)GROUPS*GPAD*4);
  unsigned* recs = (unsigned*)take((size_t)GROUPS*GCAP*4);

  // stage 0: gcnt=0 + W1 transpose + q projections
  init_kernel<<<130, 256, 0, stream>>>(
      W1, W2, al2, ar2, gcnt, W1th, W1tl, q_lt, q_rt);

  // stage 1: coarse edge partition ∥ layer-1 GEMM (independent, fused dispatch)
  gemm_p1_kernel<<<P1B + GEMMB, 256, 0, stream>>>(
      src, dst, gcnt, recs, x, W1th, W1tl, al1, ar1, feat, el1, er1);

  // stage 2: per-group LDS bucket build (no global atomics, sparse flush)
  bucket_build_kernel<<<GROUPS, 256, 0, stream>>>(recs, gcnt, cnt, bucket);

  // stage 3: layer-1 softmax + aggregate (1-wave blocks, no barriers)
  edge_agg_l1<<<N_NODES, 64, 0, stream>>>(
      (const bf16*)feat, el1, er1, cnt, bucket, b1, q_lt, q_rt, hbf, el2, er2);

  // stage 4: layer-2 softmax + aggregate (4 nodes/block — round-8 best config)
  edge_agg_l2<<<N_NODES/4, 256, 0, stream>>>(
      hbf, el2, er2, cnt, bucket, W2, b2, (float*)d_out);
}